// Round 9
// baseline (403.568 us; speedup 1.0000x reference)
//
#include <hip/hip_runtime.h>
#include <stdint.h>

#define NB      22743     // total boxes per batch (3*(19^2+38^2+76^2))
#define L0N     1083      // level0 box count (3*361)
#define L1N     5415      // level0+level1 (3*361+3*1444)
#define PRE     400
#define TOPK_N  200
#define CAP     2048      // final candidate capacity per batch
#define CAPC    2560      // conf-subset list capacity per batch
#define NCONF   2560      // conf-subset target size
#define NBATCH  8
#define NBINS1  2048      // level-1 bins: mono bits [31:21]
#define NBINS2  4096      // level-2 bins: mono bits [20:9]
#define MIN_VALID_P21 ((u32)(0xBC23D70Au >> 21))   // mono(0.01f)>>21 = 1505
#define MIN_VALID_P9  ((u32)(0xBC23D70Au >> 9))    // mono(0.01f)>>9

typedef unsigned long long u64;
typedef unsigned int u32;

__device__ __forceinline__ float sigf(float x) { return 1.0f / (1.0f + expf(-x)); }

// order-preserving f32 -> u32 mapping
__device__ __forceinline__ u32 mono32(float f) {
    u32 u = __float_as_uint(f);
    return (u & 0x80000000u) ? ~u : (u | 0x80000000u);
}
__device__ __forceinline__ float unmono(u32 m) {
    u32 u = (m & 0x80000000u) ? (m & 0x7FFFFFFFu) : ~m;
    return __uint_as_float(u);
}

// pointer to field-0 of box g in batch b, plus geometry
__device__ __forceinline__ const float* box_base(
    const float* f0, const float* f1, const float* f2,
    int b, int g, int* HW, int* cw, int* ch, float* stride, float* aw, float* ah)
{
    const float* f; int W, off, li;
    if (g < L0N)      { f = f0; W = 19; off = 0;   li = 0; *stride = 32.f; }
    else if (g < L1N) { f = f1; W = 38; off = L0N; li = 1; *stride = 16.f; }
    else              { f = f2; W = 76; off = L1N; li = 2; *stride = 8.f;  }
    const float AWt[3][3] = {{116.f,156.f,373.f},{30.f,62.f,59.f},{10.f,16.f,33.f}};
    const float AHt[3][3] = {{90.f,198.f,326.f},{61.f,45.f,119.f},{13.f,30.f,23.f}};
    int hw = W * W;
    int local = g - off;
    int a = local / hw; int r = local - a * hw;
    int h = r / W; int w = r - h * W;
    *HW = hw; *cw = w; *ch = h;
    *aw = AWt[li][a]; *ah = AHt[li][a];
    return f + (size_t)((b * 255 + a * 85) * hw + h * W + w);
}

// K1: per-batch, select the ~NCONF highest-conf boxes. The subset only feeds a
// LOWER BOUND on the 400th-best score, so any subset (including capped) is safe.
__global__ __launch_bounds__(1024) void conf_select_k(
    const float* __restrict__ f0, const float* __restrict__ f1,
    const float* __restrict__ f2, int* __restrict__ BOXL, u32* __restrict__ cntc)
{
    __shared__ u32 h[NBINS1 * 2];
    __shared__ u32 part[1024];
    __shared__ u32 selbin;
    __shared__ u32 lcnt;
    const int b = blockIdx.x;
    const int tid = threadIdx.x;
    for (int i = tid; i < NBINS1 * 2; i += 1024) h[i] = 0;
    if (tid == 0) { selbin = 0; lcnt = 0; }
    __syncthreads();

    for (int g = tid; g < NB; g += 1024) {
        int HW, cw, ch; float stride, aw, ah;
        const float* p = box_base(f0, f1, f2, b, g, &HW, &cw, &ch, &stride, &aw, &ah);
        float conf = sigf(p[4 * HW]);
        if (conf >= 0.01f)     // conf<0.01 -> every score of the box is invalid
            atomicAdd(&h[(mono32(conf) >> 21) * 2 + (tid & 1)], 1u);
    }
    __syncthreads();

    part[tid] = h[(tid*2)*2] + h[(tid*2)*2+1] + h[(tid*2+1)*2] + h[(tid*2+1)*2+1];
    __syncthreads();
    if (tid == 0) {            // downward scan, early exit (crossing is high)
        u32 cum = 0;
        for (int t = 1023; t >= 0; --t) {
            u32 c = part[t];
            if (cum + c >= NCONF) {
                u32 cb1 = h[(t*2+1)*2] + h[(t*2+1)*2+1];
                selbin = (cum + cb1 >= NCONF) ? (u32)(t*2+1) : (u32)(t*2);
                break;
            }
            cum += c;
        }   // no crossing (few valid): selbin=0 -> gather all valid
    }
    __syncthreads();

    const u32 Tc = selbin;
    for (int g = tid; g < NB; g += 1024) {
        int HW, cw, ch; float stride, aw, ah;
        const float* p = box_base(f0, f1, f2, b, g, &HW, &cw, &ch, &stride, &aw, &ah);
        float conf = sigf(p[4 * HW]);
        if (conf >= 0.01f && (mono32(conf) >> 21) >= Tc) {
            u32 pos = atomicAdd(&lcnt, 1u);
            if (pos < CAPC) BOXL[b * CAPC + pos] = g;
        }
    }
    __syncthreads();
    if (tid == 0) cntc[b] = (lcnt < CAPC) ? lcnt : CAPC;
}

// K2: score the subset, histogram valid scores at 11-bit (bits [31:21]).
__global__ __launch_bounds__(256) void subset_score_k(
    const float* __restrict__ f0, const float* __restrict__ f1,
    const float* __restrict__ f2, const int* __restrict__ BOXL,
    const u32* __restrict__ cntc, u32* __restrict__ ghist0)
{
    __shared__ u32 h[NBINS1];
    const int b = blockIdx.y;
    const int tid = threadIdx.x;
    for (int i = tid; i < NBINS1; i += 256) h[i] = 0;
    __syncthreads();

    const int idx = blockIdx.x * 256 + tid;
    const int lp = idx / 80, c = idx - lp * 80;
    const int nlist = (int)min(cntc[b], (u32)CAPC);
    if (lp < nlist) {
        int g = BOXL[b * CAPC + lp];
        int HW, cw, ch; float stride, aw, ah;
        const float* p = box_base(f0, f1, f2, b, g, &HW, &cw, &ch, &stride, &aw, &ah);
        float conf = sigf(p[4 * HW]);
        float s = conf * sigf(p[(5 + c) * HW]);
        if (s >= 0.01f) atomicAdd(&h[mono32(s) >> 21], 1u);
    }
    __syncthreads();
    u32* gh = ghist0 + b * NBINS1;
    for (int i = tid; i < NBINS1; i += 256)
        if (h[i]) atomicAdd(&gh[i], h[i]);
}

// K3: bin of the 400th-best SUBSET score -> conf-gate prefix P21 (lower bound
// on the true 400th-best score's bin; used ONLY as a gate, never as threshold).
__global__ __launch_bounds__(256) void subset_scan_k(const u32* __restrict__ ghist0,
                                                     u32* __restrict__ P21)
{
    const int b = blockIdx.x;
    const int tid = threadIdx.x;
    const u32* h = ghist0 + b * NBINS1;
    __shared__ u32 lh[NBINS1];
    __shared__ u32 part[256];
    __shared__ u32 suf[256];

    for (int i = tid; i < NBINS1; i += 256) lh[i] = h[i];
    if (tid == 0) P21[b] = MIN_VALID_P21;   // degenerate: gate = all valid boxes
    __syncthreads();

    u32 ps = 0;
    #pragma unroll
    for (int i = 0; i < 8; ++i) ps += lh[tid * 8 + i];
    part[tid] = ps;
    __syncthreads();
    if (tid == 0) {
        u32 cum = 0;
        for (int t = 255; t >= 0; --t) { suf[t] = cum; cum += part[t]; }
    }
    __syncthreads();
    if (suf[tid] < PRE && suf[tid] + part[tid] >= PRE) {   // exactly one thread
        u32 cum = suf[tid];
        for (int bin = tid * 8 + 7; bin >= tid * 8; --bin) {
            u32 c = lh[bin];
            if (cum + c >= PRE) {
                P21[b] = ((u32)bin > MIN_VALID_P21) ? (u32)bin : MIN_VALID_P21;
                break;
            }
            cum += c;
        }
    }
}

// Conf-gated full-set passes. score <= conf (cls-sigmoid < 1), so a box whose
// conf-prefix misses the gate cannot contribute any element at/above it ->
// gated histograms are EXACT for all bins >= gate.
// MODE 1: exact level-1 histogram (bits[31:21]), gate = P21 (subset bound).
// MODE 2: level-2 histogram (bits[20:9]) of elements in bin sel1.x, gate = sel1.x.
// MODE 3: gather candidates with (mono>>9) >= t23, gate = t23 at 23 bits.
template<int MODE>
__global__ __launch_bounds__(256) void gated_pass(
    const float* __restrict__ f0, const float* __restrict__ f1,
    const float* __restrict__ f2, const u32* __restrict__ P21,
    const int2* __restrict__ sel1, const u32* __restrict__ t23,
    u32* __restrict__ ghist, u32* __restrict__ cnt, u64* __restrict__ cand)
{
    __shared__ u32 h[(MODE == 1) ? NBINS1 : ((MODE == 2) ? NBINS2 : 1)];
    const int b = blockIdx.y;
    const int tid = threadIdx.x;
    if (MODE == 1) { for (int i = tid; i < NBINS1; i += 256) h[i] = 0; __syncthreads(); }
    if (MODE == 2) { for (int i = tid; i < NBINS2; i += 256) h[i] = 0; __syncthreads(); }

    const int g = blockIdx.x * 256 + tid;
    if (g < NB) {
        int HW, cw, ch; float stride, aw, ah;
        const float* p = box_base(f0, f1, f2, b, g, &HW, &cw, &ch, &stride, &aw, &ah);
        float conf = sigf(p[4 * HW]);
        if (conf >= 0.01f) {
            u32 mc = mono32(conf);
            u32 gate1 = 0, T = 0;
            bool do_box;
            if (MODE == 1)      { gate1 = P21[b];          do_box = ((mc >> 21) >= gate1); }
            else if (MODE == 2) { gate1 = (u32)sel1[b].x;  do_box = ((mc >> 21) >= gate1); }
            else                { T = t23[b];              do_box = ((mc >> 9)  >= T); }
            if (do_box) {
                for (int c = 0; c < 80; ++c) {
                    float s = conf * sigf(p[(5 + c) * HW]);
                    // sub-threshold scores are -1.0 sentinels in the reference:
                    // inert in NMS, emitted as pad rows -> same as our pads, skip.
                    if (s < 0.01f) continue;
                    u32 m = mono32(s);
                    if (MODE == 1) {
                        atomicAdd(&h[m >> 21], 1u);
                    } else if (MODE == 2) {
                        if ((m >> 21) == gate1) atomicAdd(&h[(m >> 9) & 0xFFFu], 1u);
                    } else {
                        if ((m >> 9) >= T) {
                            u32 pos = atomicAdd(&cnt[b], 1u);
                            if (pos < CAP) {
                                u32 e = (u32)(g * 80 + c);   // reference flat index
                                cand[b * CAP + pos] = ((u64)m << 32) | (u64)(0xFFFFFFFFu - e);
                            }
                        }
                    }
                }
            }
        }
    }
    if (MODE == 1) {
        __syncthreads();
        u32* gh = ghist + b * NBINS1;
        for (int i = tid; i < NBINS1; i += 256)
            if (h[i]) atomicAdd(&gh[i], h[i]);
    }
    if (MODE == 2) {
        __syncthreads();
        u32* gh = ghist + b * NBINS2;
        for (int i = tid; i < NBINS2; i += 256)
            if (h[i]) atomicAdd(&gh[i], h[i]);
    }
}

// Exact pivot scans (as in the round-3/6 passing kernel).
// LEVEL 1 (2048 bins): sel1 = (exact bin of 400th element, cumAbove).
// LEVEL 2 (4096 bins, need = PRE - sel1.y): t23 = clamped 23-bit threshold.
template<int LEVEL>
__global__ __launch_bounds__(256) void scan_k(const u32* __restrict__ ghist,
                                              int2* __restrict__ sel1,
                                              u32* __restrict__ t23)
{
    constexpr int NB_ = (LEVEL == 1) ? NBINS1 : NBINS2;
    constexpr int CH  = NB_ / 256;
    const int b = blockIdx.x;
    const int tid = threadIdx.x;
    const u32* h = ghist + b * NB_;
    __shared__ u32 lh[NB_];
    __shared__ u32 part[256];
    __shared__ u32 suf[256];

    const u32 need = (LEVEL == 1) ? (u32)PRE : (u32)(PRE - sel1[b].y);

    for (int i = tid; i < NB_; i += 256) lh[i] = h[i];
    if (tid == 0) {   // defaults for the degenerate (<need total) case
        if (LEVEL == 1) sel1[b] = make_int2(0, 0);
        else            t23[b]  = MIN_VALID_P9;     // gather all valid
    }
    __syncthreads();

    u32 ps = 0;
    #pragma unroll
    for (int i = 0; i < CH; ++i) ps += lh[tid * CH + i];
    part[tid] = ps;
    __syncthreads();

    if (tid == 0) {
        u32 cum = 0;
        for (int t = 255; t >= 0; --t) { suf[t] = cum; cum += part[t]; }
    }
    __syncthreads();

    if (suf[tid] < need && suf[tid] + part[tid] >= need) {   // exactly one thread
        u32 cum = suf[tid];
        for (int bin = tid * CH + CH - 1; bin >= tid * CH; --bin) {
            u32 c = lh[bin];
            if (cum + c >= need) {
                if (LEVEL == 1) {
                    sel1[b] = make_int2(bin, (int)cum);
                } else {
                    u32 t = ((u32)sel1[b].x << 12) | (u32)bin;
                    t23[b] = (t > MIN_VALID_P9) ? t : MIN_VALID_P9;
                }
                break;
            }
            cum += c;
        }
    }
}

// K5: fused final stage per batch: rank-sort candidates (exact (val desc, idx
// asc) order), decode top-400 boxes, suppression matrix, serial greedy NMS over
// register bitmasks, rank-select top-200, write output.
__global__ __launch_bounds__(512) void fused_final_k(
    const float* __restrict__ f0, const float* __restrict__ f1,
    const float* __restrict__ f2, const u32* __restrict__ cnt,
    const u64* __restrict__ cand, float* __restrict__ out)
{
    __shared__ u64 keys[CAP];
    __shared__ u64 SKEY[PRE];
    __shared__ float4 BX[PRE];
    __shared__ float VALs[PRE];
    __shared__ int LC[PRE];
    __shared__ u64 SUP[PRE][7];
    __shared__ u64 VBM[8];
    __shared__ u64 KBM[8];

    const int b = blockIdx.x;
    const int tid = threadIdx.x;
    const int n = (int)min(cnt[b], (u32)CAP);

    for (int i = tid; i < n; i += 512) keys[i] = cand[b * CAP + i];
    for (int i = tid; i < PRE; i += 512) SKEY[i] = 0ull;
    if (tid < 8) { VBM[tid] = 0ull; KBM[tid] = 0ull; }
    __syncthreads();

    // rank sort: keys unique; LDS broadcast reads, 4x unrolled
    for (int e = tid; e < n; e += 512) {
        u64 my = keys[e];
        int r = 0, k = 0;
        for (; k + 4 <= n; k += 4)
            r += (int)(keys[k] > my) + (int)(keys[k+1] > my)
               + (int)(keys[k+2] > my) + (int)(keys[k+3] > my);
        for (; k < n; ++k) r += (int)(keys[k] > my);
        if (r < PRE) SKEY[r] = my;
    }
    __syncthreads();

    // decode top-400 to corner boxes + valid ballot
    bool valid = false;
    if (tid < PRE) {
        u64 kk = SKEY[tid];
        float v; int g, c;
        if (kk) {
            u32 m = (u32)(kk >> 32);
            u32 e = 0xFFFFFFFFu - (u32)(kk & 0xFFFFFFFFu);
            v = unmono(m); g = (int)(e / 80u); c = (int)(e - (u32)g * 80u);
            valid = true;                       // gathered scores all >= 0.01
        } else { v = -1.0f; g = 0; c = 0; }
        VALs[tid] = v; LC[tid] = c;
        int HW, cw, ch; float stride, aw, ah;
        const float* p = box_base(f0, f1, f2, b, g, &HW, &cw, &ch, &stride, &aw, &ah);
        float cx = (sigf(p[0])  + (float)cw) * stride;
        float cy = (sigf(p[HW]) + (float)ch) * stride;
        float bw = expf(p[2 * HW]) * aw;
        float bh = expf(p[3 * HW]) * ah;
        BX[tid] = make_float4(cx - bw * 0.5f, cy - bh * 0.5f,
                              cx + bw * 0.5f, cy + bh * 0.5f);
    }
    u64 bal = __ballot(valid);
    if ((tid & 63) == 0 && (tid >> 6) < 7) VBM[tid >> 6] = bal;
    __syncthreads();

    // suppression matrix: SUP[i][w] bit (j-64w) = i suppresses j (j>i).
    // Uniform j across the wave -> LDS broadcast reads.
    if (tid < PRE) {
        const int i = tid;
        float4 bi = BX[i]; int ci = LC[i];
        float ai = fmaxf(bi.z - bi.x, 0.f) * fmaxf(bi.w - bi.y, 0.f);
        #pragma unroll
        for (int w = 0; w < 7; ++w) {
            u64 mask = 0ull;
            if (w >= (i >> 6)) {
                int jbase = w << 6;
                int j1 = (jbase + 64 < PRE) ? (jbase + 64) : PRE;
                for (int j = jbase; j < j1; ++j) {
                    float4 bj = BX[j];
                    bool ok = (LC[j] == ci) && (j > i);
                    float ix1 = fmaxf(bi.x, bj.x), iy1 = fmaxf(bi.y, bj.y);
                    float ix2 = fminf(bi.z, bj.z), iy2 = fminf(bi.w, bj.w);
                    float inter = fmaxf(ix2 - ix1, 0.f) * fmaxf(iy2 - iy1, 0.f);
                    float aj = fmaxf(bj.z - bj.x, 0.f) * fmaxf(bj.w - bj.y, 0.f);
                    float iou = inter / fmaxf(ai + aj - inter, 1e-9f);
                    if (ok && iou > 0.45f) mask |= 1ull << (j - jbase);
                }
            }
            SUP[i][w] = mask;
        }
    }
    __syncthreads();

    // serial greedy over register bitmasks, 2-deep A/B row prefetch
    if (tid == 0) {
        u64 kp[7], A[7], B[7];
        #pragma unroll
        for (int w = 0; w < 7; ++w) kp[w] = VBM[w];
        #pragma unroll
        for (int w = 0; w < 7; ++w) A[w] = SUP[0][w];
        #pragma unroll
        for (int w = 0; w < 7; ++w) B[w] = SUP[1][w];
        #pragma unroll
        for (int w = 0; w < 7; ++w) {
            const int base = w << 6;
            const int lim = (w == 6) ? 16 : 64;   // PRE = 400
            for (int bi = 0; bi < lim; bi += 2) {
                int i = base + bi;
                if ((kp[w] >> bi) & 1) {
                    #pragma unroll
                    for (int w2 = 0; w2 < 7; ++w2) kp[w2] &= ~A[w2];
                }
                int ip2 = (i + 2 < PRE) ? (i + 2) : (PRE - 1);
                #pragma unroll
                for (int w2 = 0; w2 < 7; ++w2) A[w2] = SUP[ip2][w2];
                if ((kp[w] >> (bi + 1)) & 1) {
                    #pragma unroll
                    for (int w2 = 0; w2 < 7; ++w2) kp[w2] &= ~B[w2];
                }
                int ip3 = (i + 3 < PRE) ? (i + 3) : (PRE - 1);
                #pragma unroll
                for (int w2 = 0; w2 < 7; ++w2) B[w2] = SUP[ip3][w2];
            }
        }
        #pragma unroll
        for (int w = 0; w < 7; ++w) KBM[w] = kp[w];
    }
    __syncthreads();

    // rank-select top-200 (kept in order, then pads) and write output
    int totk = 0;
    #pragma unroll
    for (int w = 0; w < 7; ++w) totk += __popcll(KBM[w]);
    for (int j = tid; j < PRE; j += 512) {
        int w = j >> 6, bi = j & 63;
        int pre_kept = 0;
        for (int ww = 0; ww < w; ++ww) pre_kept += __popcll(KBM[ww]);
        u64 kw = KBM[w];
        pre_kept += __popcll(kw & ((1ull << bi) - 1ull));
        bool kept = (kw >> bi) & 1;
        int slot = kept ? pre_kept : (totk + j - pre_kept);
        if (slot < TOPK_N) {
            float* o = out + ((size_t)b * TOPK_N + slot) * 6;
            if (kept) {
                float4 bx = BX[j];
                o[0] = bx.x; o[1] = bx.y; o[2] = bx.z; o[3] = bx.w;
                o[4] = VALs[j]; o[5] = (float)LC[j];
            } else {
                o[0] = 0.f; o[1] = 0.f; o[2] = 0.f; o[3] = 0.f; o[4] = 0.f; o[5] = -1.f;
            }
        }
    }
}

extern "C" void kernel_launch(void* const* d_in, const int* in_sizes, int n_in,
                              void* d_out, int out_size, void* d_ws, size_t ws_size,
                              hipStream_t stream)
{
    const float* f0 = (const float*)d_in[0];
    const float* f1 = (const float*)d_in[1];
    const float* f2 = (const float*)d_in[2];
    float* out = (float*)d_out;
    char* ws = (char*)d_ws;

    // ws layout (~465 KB total)
    u32*  ghist0 = (u32*)(ws);                //      0: 8*2048*4 = 65536 (subset)
    u32*  ghist1 = (u32*)(ws + 65536);        //  65536: 8*2048*4 = 65536 (level-1)
    u32*  ghist2 = (u32*)(ws + 131072);       // 131072: 8*4096*4 = 131072 (level-2)
    u32*  cntc   = (u32*)(ws + 262144);       // 262144: 32
    u32*  cnt    = (u32*)(ws + 262176);       // 262176: 32
    u32*  P21    = (u32*)(ws + 262208);       // 262208: 32
    u32*  t23    = (u32*)(ws + 262240);       // 262240: 32
    int2* sel1   = (int2*)(ws + 262272);      // 262272: 64
    int*  BOXL   = (int*)(ws + 262336);       // 262336: 8*2560*4 = 81920
    u64*  cand   = (u64*)(ws + 344256);       // 344256: 8*2048*8 = 131072 -> 475328

    hipMemsetAsync(ws, 0, 262208, stream);    // zero ghist0/1/2, cntc, cnt

    dim3 gridNB((NB + 255) / 256, NBATCH);
    conf_select_k<<<NBATCH, 1024, 0, stream>>>(f0, f1, f2, BOXL, cntc);
    subset_score_k<<<dim3(CAPC * 80 / 256, NBATCH), 256, 0, stream>>>(
        f0, f1, f2, BOXL, cntc, ghist0);
    subset_scan_k<<<NBATCH, 256, 0, stream>>>(ghist0, P21);
    gated_pass<1><<<gridNB, 256, 0, stream>>>(f0, f1, f2, P21, sel1, t23, ghist1, cnt, cand);
    scan_k<1><<<NBATCH, 256, 0, stream>>>(ghist1, sel1, t23);
    gated_pass<2><<<gridNB, 256, 0, stream>>>(f0, f1, f2, P21, sel1, t23, ghist2, cnt, cand);
    scan_k<2><<<NBATCH, 256, 0, stream>>>(ghist2, sel1, t23);
    gated_pass<3><<<gridNB, 256, 0, stream>>>(f0, f1, f2, P21, sel1, t23, ghist1, cnt, cand);
    fused_final_k<<<NBATCH, 512, 0, stream>>>(f0, f1, f2, cnt, cand, out);
}

// Round 10
// 322.463 us; speedup vs baseline: 1.2515x; 1.2515x over previous
//
#include <hip/hip_runtime.h>
#include <stdint.h>

#define NB      22743     // total boxes per batch (3*(19^2+38^2+76^2))
#define L0N     1083      // level0 box count (3*361)
#define L1N     5415      // level0+level1 (3*361+3*1444)
#define PRE     400
#define TOPK_N  200
#define CAP     2048      // final candidate capacity per batch
#define CAPC    2560      // conf-subset list capacity per batch
#define NCONF   2560      // conf-subset target size
#define NBATCH  8
#define NBINS1  2048      // level-1 bins: mono bits [31:21]
#define NBINS2  4096      // level-2 bins: mono bits [20:9]
#define MIN_VALID_P9  ((u32)(0xBC23D70Au >> 9))    // mono(0.01f)>>9

typedef unsigned long long u64;
typedef unsigned int u32;

__device__ __forceinline__ float sigf(float x) { return 1.0f / (1.0f + expf(-x)); }

// order-preserving f32 -> u32 mapping
__device__ __forceinline__ u32 mono32(float f) {
    u32 u = __float_as_uint(f);
    return (u & 0x80000000u) ? ~u : (u | 0x80000000u);
}
__device__ __forceinline__ float unmono(u32 m) {
    u32 u = (m & 0x80000000u) ? (m & 0x7FFFFFFFu) : ~m;
    return __uint_as_float(u);
}

// per-level specialized box base: all divisors compile-time -> magic-mul
template<int LI, int W>
__device__ __forceinline__ const float* bb_t(const float* f, int b, int local,
    int* HW, int* cw, int* ch, float* stride, float* aw, float* ah)
{
    constexpr int hw = W * W;
    int a = local / hw; int r = local - a * hw;
    int h = r / W; int w = r - h * W;
    *HW = hw; *cw = w; *ch = h;
    *stride = (LI == 0) ? 32.f : ((LI == 1) ? 16.f : 8.f);
    const float AWt[3][3] = {{116.f,156.f,373.f},{30.f,62.f,59.f},{10.f,16.f,33.f}};
    const float AHt[3][3] = {{90.f,198.f,326.f},{61.f,45.f,119.f},{13.f,30.f,23.f}};
    *aw = AWt[LI][a]; *ah = AHt[LI][a];
    return f + (size_t)((b * 255 + a * 85) * hw) + r;
}

__device__ __forceinline__ const float* box_base2(
    const float* f0, const float* f1, const float* f2,
    int b, int g, int* HW, int* cw, int* ch, float* stride, float* aw, float* ah)
{
    if (g < L0N)      return bb_t<0,19>(f0, b, g,       HW, cw, ch, stride, aw, ah);
    else if (g < L1N) return bb_t<1,38>(f1, b, g - L0N, HW, cw, ch, stride, aw, ah);
    else              return bb_t<2,76>(f2, b, g - L1N, HW, cw, ch, stride, aw, ah);
}

// conf-only loader (constant-divisor address math)
__device__ __forceinline__ float get_conf(const float* f0, const float* f1,
                                          const float* f2, int b, int g)
{
    const float* p;
    if (g < L0N)      { int a = g / 361;           int r = g - a * 361;
                        p = f0 + (size_t)((b*255 + a*85 + 4) * 361)  + r; }
    else if (g < L1N) { int t = g - L0N; int a = t / 1444; int r = t - a * 1444;
                        p = f1 + (size_t)((b*255 + a*85 + 4) * 1444) + r; }
    else              { int t = g - L1N; int a = t / 5776; int r = t - a * 5776;
                        p = f2 + (size_t)((b*255 + a*85 + 4) * 5776) + r; }
    return sigf(*p);
}

// K1: per-batch, select the ~NCONF highest-conf boxes. Subset completeness
// argument: any element outside the subset has score < conf < C* (the lowest
// selected conf), and the subset's 400th-best score S' >= C* in practice, so
// the exact threshold derived from the subset gates a CAP-bounded gather
// (validated empirically by the round-3/6 passing lineage: ~400-450 gathered).
__global__ __launch_bounds__(1024) void conf_select_k(
    const float* __restrict__ f0, const float* __restrict__ f1,
    const float* __restrict__ f2, int* __restrict__ BOXL, u32* __restrict__ cntc)
{
    __shared__ u32 h[NBINS1 * 2];
    __shared__ u32 part[1024];
    __shared__ u32 selbin;
    __shared__ u32 lcnt;
    const int b = blockIdx.x;
    const int tid = threadIdx.x;
    for (int i = tid; i < NBINS1 * 2; i += 1024) h[i] = 0;
    if (tid == 0) { selbin = 0; lcnt = 0; }
    __syncthreads();

    for (int g = tid; g < NB; g += 1024) {
        float conf = get_conf(f0, f1, f2, b, g);
        if (conf >= 0.01f)     // conf<0.01 -> every score of the box is invalid
            atomicAdd(&h[(mono32(conf) >> 21) * 2 + (tid & 1)], 1u);
    }
    __syncthreads();

    part[tid] = h[(tid*2)*2] + h[(tid*2)*2+1] + h[(tid*2+1)*2] + h[(tid*2+1)*2+1];
    __syncthreads();
    if (tid == 0) {            // downward scan, early exit (crossing is high)
        u32 cum = 0;
        for (int t = 1023; t >= 0; --t) {
            u32 c = part[t];
            if (cum + c >= NCONF) {
                u32 cb1 = h[(t*2+1)*2] + h[(t*2+1)*2+1];
                selbin = (cum + cb1 >= NCONF) ? (u32)(t*2+1) : (u32)(t*2);
                break;
            }
            cum += c;
        }   // no crossing (few valid): selbin=0 -> gather all valid
    }
    __syncthreads();

    const u32 Tc = selbin;
    for (int g = tid; g < NB; g += 1024) {
        float conf = get_conf(f0, f1, f2, b, g);
        if (conf >= 0.01f && (mono32(conf) >> 21) >= Tc) {
            u32 pos = atomicAdd(&lcnt, 1u);
            if (pos < CAPC) BOXL[b * CAPC + pos] = g;
        }
    }
    __syncthreads();
    if (tid == 0) cntc[b] = (lcnt < CAPC) ? lcnt : CAPC;
}

// K2: score the subset, histogram valid scores at bits [31:21].
__global__ __launch_bounds__(256) void subset_score_k(
    const float* __restrict__ f0, const float* __restrict__ f1,
    const float* __restrict__ f2, const int* __restrict__ BOXL,
    const u32* __restrict__ cntc, u32* __restrict__ ghist0)
{
    __shared__ u32 h[NBINS1];
    const int b = blockIdx.y;
    const int tid = threadIdx.x;
    for (int i = tid; i < NBINS1; i += 256) h[i] = 0;
    __syncthreads();

    const int idx = blockIdx.x * 256 + tid;
    const int lp = idx / 80, c = idx - lp * 80;
    const int nlist = (int)min(cntc[b], (u32)CAPC);
    if (lp < nlist) {
        int g = BOXL[b * CAPC + lp];
        int HW, cw, ch; float stride, aw, ah;
        const float* p = box_base2(f0, f1, f2, b, g, &HW, &cw, &ch, &stride, &aw, &ah);
        float conf = sigf(p[4 * HW]);
        float s = conf * sigf(p[(5 + c) * HW]);
        if (s >= 0.01f) atomicAdd(&h[mono32(s) >> 21], 1u);
    }
    __syncthreads();
    u32* gh = ghist0 + b * NBINS1;
    for (int i = tid; i < NBINS1; i += 256)
        if (h[i]) atomicAdd(&gh[i], h[i]);
}

// K4: level-2 refinement over the SUBSET only: histogram bits [20:9] of
// subset elements whose level-1 bin == sel1[b].x. Bit-identical score math.
__global__ __launch_bounds__(256) void subset_p2_k(
    const float* __restrict__ f0, const float* __restrict__ f1,
    const float* __restrict__ f2, const int* __restrict__ BOXL,
    const u32* __restrict__ cntc, const int2* __restrict__ sel1,
    u32* __restrict__ ghist2)
{
    __shared__ u32 h[NBINS2];
    const int b = blockIdx.y;
    const int tid = threadIdx.x;
    for (int i = tid; i < NBINS2; i += 256) h[i] = 0;
    __syncthreads();

    const int idx = blockIdx.x * 256 + tid;
    const int lp = idx / 80, c = idx - lp * 80;
    const int nlist = (int)min(cntc[b], (u32)CAPC);
    const u32 b1 = (u32)sel1[b].x;
    if (lp < nlist) {
        int g = BOXL[b * CAPC + lp];
        int HW, cw, ch; float stride, aw, ah;
        const float* p = box_base2(f0, f1, f2, b, g, &HW, &cw, &ch, &stride, &aw, &ah);
        float conf = sigf(p[4 * HW]);
        float s = conf * sigf(p[(5 + c) * HW]);
        if (s >= 0.01f) {
            u32 m = mono32(s);
            if ((m >> 21) == b1) atomicAdd(&h[(m >> 9) & 0xFFFu], 1u);
        }
    }
    __syncthreads();
    u32* gh = ghist2 + b * NBINS2;
    for (int i = tid; i < NBINS2; i += 256)
        if (h[i]) atomicAdd(&gh[i], h[i]);
}

// Exact pivot scans over the subset histograms (same code as passing lineage).
// LEVEL 1 (2048 bins): sel1 = (bin of subset 400th element, cumAbove).
// LEVEL 2 (4096 bins, need = PRE - sel1.y): t23 = clamped 23-bit threshold.
template<int LEVEL>
__global__ __launch_bounds__(256) void scan_k(const u32* __restrict__ ghist,
                                              int2* __restrict__ sel1,
                                              u32* __restrict__ t23)
{
    constexpr int NB_ = (LEVEL == 1) ? NBINS1 : NBINS2;
    constexpr int CH  = NB_ / 256;
    const int b = blockIdx.x;
    const int tid = threadIdx.x;
    const u32* h = ghist + b * NB_;
    __shared__ u32 lh[NB_];
    __shared__ u32 part[256];
    __shared__ u32 suf[256];

    const u32 need = (LEVEL == 1) ? (u32)PRE : (u32)(PRE - sel1[b].y);

    for (int i = tid; i < NB_; i += 256) lh[i] = h[i];
    if (tid == 0) {   // defaults for the degenerate (<need total) case
        if (LEVEL == 1) sel1[b] = make_int2(0, 0);
        else            t23[b]  = MIN_VALID_P9;     // gather all valid
    }
    __syncthreads();

    u32 ps = 0;
    #pragma unroll
    for (int i = 0; i < CH; ++i) ps += lh[tid * CH + i];
    part[tid] = ps;
    __syncthreads();

    if (tid == 0) {
        u32 cum = 0;
        for (int t = 255; t >= 0; --t) { suf[t] = cum; cum += part[t]; }
    }
    __syncthreads();

    if (suf[tid] < need && suf[tid] + part[tid] >= need) {   // exactly one thread
        u32 cum = suf[tid];
        for (int bin = tid * CH + CH - 1; bin >= tid * CH; --bin) {
            u32 c = lh[bin];
            if (cum + c >= need) {
                if (LEVEL == 1) {
                    sel1[b] = make_int2(bin, (int)cum);
                } else {
                    u32 t = ((u32)sel1[b].x << 12) | (u32)bin;
                    t23[b] = (t > MIN_VALID_P9) ? t : MIN_VALID_P9;
                }
                break;
            }
            cum += c;
        }
    }
}

// K6: full-set gather. score <= conf, so (mono_conf>>9) < t23 implies no score
// of the box can reach the threshold -> ~99% of boxes skip the class loop.
__global__ __launch_bounds__(256) void gather_k(
    const float* __restrict__ f0, const float* __restrict__ f1,
    const float* __restrict__ f2, const u32* __restrict__ t23,
    u32* __restrict__ cnt, u64* __restrict__ cand)
{
    const int b = blockIdx.y;
    const int g = blockIdx.x * 256 + threadIdx.x;
    if (g >= NB) return;
    float conf = get_conf(f0, f1, f2, b, g);
    if (conf < 0.01f) return;
    const u32 T = t23[b];
    if ((mono32(conf) >> 9) < T) return;
    int HW, cw, ch; float stride, aw, ah;
    const float* p = box_base2(f0, f1, f2, b, g, &HW, &cw, &ch, &stride, &aw, &ah);
    for (int c = 0; c < 80; ++c) {
        float s = conf * sigf(p[(5 + c) * HW]);
        // sub-threshold scores are -1.0 sentinels in the reference: inert in
        // NMS, emitted as pad rows -> interchangeable with our pads, skip.
        if (s < 0.01f) continue;
        u32 m = mono32(s);
        if ((m >> 9) >= T) {
            u32 pos = atomicAdd(&cnt[b], 1u);
            if (pos < CAP) {
                u32 e = (u32)(g * 80 + c);   // reference flat index
                cand[b * CAP + pos] = ((u64)m << 32) | (u64)(0xFFFFFFFFu - e);
            }
        }
    }
}

// K7: fused final stage: rank-sort (exact (val desc, idx asc)), decode top-400,
// SUP matrix in LDS (w-outer mapping -> broadcast reads), LANE-PARALLEL greedy
// NMS (lane l owns keep-word l; 1 conflict-free ds_read_b64 per box, 4-deep
// prefetch, __shfl broadcast of the owner word), rank-select top-200, output.
__global__ __launch_bounds__(512) void final3_k(
    const float* __restrict__ f0, const float* __restrict__ f1,
    const float* __restrict__ f2, const u32* __restrict__ cnt,
    const u64* __restrict__ cand, float* __restrict__ out)
{
    __shared__ u64 keys[CAP];
    __shared__ u64 SKEY[PRE];
    __shared__ float4 BX[PRE];
    __shared__ float VALs[PRE];
    __shared__ int LC[PRE];
    __shared__ u64 SUP[PRE][7];
    __shared__ u64 VBM[8];
    __shared__ u64 KBM[8];

    const int b = blockIdx.x;
    const int tid = threadIdx.x;
    const int n = (int)min(cnt[b], (u32)CAP);

    for (int i = tid; i < n; i += 512) keys[i] = cand[b * CAP + i];
    for (int i = tid; i < PRE; i += 512) SKEY[i] = 0ull;
    if (tid < 8) { VBM[tid] = 0ull; KBM[tid] = 0ull; }
    __syncthreads();

    // rank sort: keys unique; LDS broadcast reads, 4x unrolled
    for (int e = tid; e < n; e += 512) {
        u64 my = keys[e];
        int r = 0, k = 0;
        for (; k + 4 <= n; k += 4)
            r += (int)(keys[k] > my) + (int)(keys[k+1] > my)
               + (int)(keys[k+2] > my) + (int)(keys[k+3] > my);
        for (; k < n; ++k) r += (int)(keys[k] > my);
        if (r < PRE) SKEY[r] = my;
    }
    __syncthreads();

    // decode top-400 to corner boxes + valid ballot
    bool valid = false;
    if (tid < PRE) {
        u64 kk = SKEY[tid];
        float v; int g, c;
        if (kk) {
            u32 m = (u32)(kk >> 32);
            u32 e = 0xFFFFFFFFu - (u32)(kk & 0xFFFFFFFFu);
            v = unmono(m); g = (int)(e / 80u); c = (int)(e - (u32)g * 80u);
            valid = true;                       // gathered scores all >= 0.01
        } else { v = -1.0f; g = 0; c = 0; }
        VALs[tid] = v; LC[tid] = c;
        int HW, cw, ch; float stride, aw, ah;
        const float* p = box_base2(f0, f1, f2, b, g, &HW, &cw, &ch, &stride, &aw, &ah);
        float cx = (sigf(p[0])  + (float)cw) * stride;
        float cy = (sigf(p[HW]) + (float)ch) * stride;
        float bw = expf(p[2 * HW]) * aw;
        float bh = expf(p[3 * HW]) * ah;
        BX[tid] = make_float4(cx - bw * 0.5f, cy - bh * 0.5f,
                              cx + bw * 0.5f, cy + bh * 0.5f);
    }
    u64 bal = __ballot(valid);
    if ((tid & 63) == 0 && (tid >> 6) < 7) VBM[tid >> 6] = bal;
    __syncthreads();

    // SUP matrix: t = w*PRE + i -> lanes share w and the j-range (broadcast)
    for (int t = tid; t < 7 * PRE; t += 512) {
        int w = t / PRE, i = t - w * PRE;
        u64 mask = 0ull;
        if (w >= (i >> 6)) {
            float4 bi = BX[i]; int ci = LC[i];
            float ai = fmaxf(bi.z - bi.x, 0.f) * fmaxf(bi.w - bi.y, 0.f);
            int jbase = w << 6;
            int j1 = (jbase + 64 < PRE) ? (jbase + 64) : PRE;
            int j0 = (jbase > i + 1) ? jbase : (i + 1);
            for (int j = j0; j < j1; ++j) {
                float4 bj = BX[j];
                float ix1 = fmaxf(bi.x, bj.x), iy1 = fmaxf(bi.y, bj.y);
                float ix2 = fminf(bi.z, bj.z), iy2 = fminf(bi.w, bj.w);
                float inter = fmaxf(ix2 - ix1, 0.f) * fmaxf(iy2 - iy1, 0.f);
                float aj = fmaxf(bj.z - bj.x, 0.f) * fmaxf(bj.w - bj.y, 0.f);
                float iou = inter / fmaxf(ai + aj - inter, 1e-9f);
                if ((LC[j] == ci) && iou > 0.45f) mask |= 1ull << (j - jbase);
            }
        }
        SUP[i][w] = mask;
    }
    __syncthreads();

    // lane-parallel greedy: lane l owns word l of the keep mask
    if (tid < 64) {
        const int l = tid;
        const bool own = (l < 7);
        u64 kpl = own ? VBM[l] : 0ull;
        u64 r0 = own ? SUP[0][l] : 0ull;
        u64 r1 = own ? SUP[1][l] : 0ull;
        u64 r2 = own ? SUP[2][l] : 0ull;
        u64 r3 = own ? SUP[3][l] : 0ull;
        for (int i = 0; i < PRE; ++i) {
            u64 row = r0;
            r0 = r1; r1 = r2; r2 = r3;
            int nx = (i + 4 < PRE) ? (i + 4) : (PRE - 1);
            r3 = own ? SUP[nx][l] : 0ull;
            u64 kw = __shfl(kpl, i >> 6);      // owner word, uniform across wave
            if ((kw >> (i & 63)) & 1ull)       // box i kept&valid -> suppress
                kpl &= ~row;
        }
        if (own) KBM[l] = kpl;
    }
    __syncthreads();

    // rank-select top-200 (kept in order, then pads) and write output
    int totk = 0;
    #pragma unroll
    for (int w = 0; w < 7; ++w) totk += __popcll(KBM[w]);
    for (int j = tid; j < PRE; j += 512) {
        int w = j >> 6, bi = j & 63;
        int pre_kept = 0;
        for (int ww = 0; ww < w; ++ww) pre_kept += __popcll(KBM[ww]);
        u64 kw = KBM[w];
        pre_kept += __popcll(kw & ((1ull << bi) - 1ull));
        bool kept = (kw >> bi) & 1;
        int slot = kept ? pre_kept : (totk + j - pre_kept);
        if (slot < TOPK_N) {
            float* o = out + ((size_t)b * TOPK_N + slot) * 6;
            if (kept) {
                float4 bx = BX[j];
                o[0] = bx.x; o[1] = bx.y; o[2] = bx.z; o[3] = bx.w;
                o[4] = VALs[j]; o[5] = (float)LC[j];
            } else {
                o[0] = 0.f; o[1] = 0.f; o[2] = 0.f; o[3] = 0.f; o[4] = 0.f; o[5] = -1.f;
            }
        }
    }
}

extern "C" void kernel_launch(void* const* d_in, const int* in_sizes, int n_in,
                              void* d_out, int out_size, void* d_ws, size_t ws_size,
                              hipStream_t stream)
{
    const float* f0 = (const float*)d_in[0];
    const float* f1 = (const float*)d_in[1];
    const float* f2 = (const float*)d_in[2];
    float* out = (float*)d_out;
    char* ws = (char*)d_ws;

    // ws layout (~400 KB total)
    u32*  ghist0 = (u32*)(ws);                //      0: 8*2048*4 = 65536 (subset L1)
    u32*  ghist2 = (u32*)(ws + 65536);        //  65536: 8*4096*4 = 131072 (subset L2)
    u32*  cntc   = (u32*)(ws + 196608);       // 196608: 32
    u32*  cnt    = (u32*)(ws + 196640);       // 196640: 32
    int2* sel1   = (int2*)(ws + 196672);      // 196672: 64
    u32*  t23    = (u32*)(ws + 196736);       // 196736: 32
    int*  BOXL   = (int*)(ws + 196768);       // 196768: 8*2560*4 = 81920
    u64*  cand   = (u64*)(ws + 278688);       // 278688: 8*2048*8 = 131072 -> 409760

    hipMemsetAsync(ws, 0, 196672, stream);    // zero ghist0, ghist2, cntc, cnt

    conf_select_k<<<NBATCH, 1024, 0, stream>>>(f0, f1, f2, BOXL, cntc);
    subset_score_k<<<dim3(CAPC * 80 / 256, NBATCH), 256, 0, stream>>>(
        f0, f1, f2, BOXL, cntc, ghist0);
    scan_k<1><<<NBATCH, 256, 0, stream>>>(ghist0, sel1, t23);
    subset_p2_k<<<dim3(CAPC * 80 / 256, NBATCH), 256, 0, stream>>>(
        f0, f1, f2, BOXL, cntc, sel1, ghist2);
    scan_k<2><<<NBATCH, 256, 0, stream>>>(ghist2, sel1, t23);
    gather_k<<<dim3((NB + 255) / 256, NBATCH), 256, 0, stream>>>(
        f0, f1, f2, t23, cnt, cand);
    final3_k<<<NBATCH, 512, 0, stream>>>(f0, f1, f2, cnt, cand, out);
}